// Round 1
// baseline (380.404 us; speedup 1.0000x reference)
//
#include <hip/hip_runtime.h>

// Problem constants (from setup_inputs): B=32, H=W=1024, N=96 boxes/batch.
#define BATCH 32
#define HDIM 1024
#define WDIM 1024
#define NBOX 96
#define THREADS 256
#define NSLICE 8   // row-slices per box: bounds worst-case (full-image box) block work to ~512 KB

// ---------------------------------------------------------------------------
// Kernel 0: zero the per-box accumulators in workspace (ws is poisoned 0xAA).
// ---------------------------------------------------------------------------
__global__ void zero_ws_kernel(float* __restrict__ ws) {
    int i = blockIdx.x * blockDim.x + threadIdx.x;
    if (i < BATCH * NBOX) ws[i] = 0.0f;
}

// ---------------------------------------------------------------------------
// Kernel 1: DIRECT box summation — no prefix scans, no LDS, no barriers.
// box_sum(b,n) = sum of img[b, y1:y2, x1:x2].
// Grid: (BATCH*NBOX, NSLICE). Block = 256 threads = 4 waves.
// Row decomposition: slice s + wave w owns rows y1 + (s*4 + w) + 32k,
// so the 4 waves of a block read 4 adjacent rows (L2-friendly) and the 8
// slice-blocks of one box split its area evenly (worst box: 8 x 512 KB).
// Lanes stride columns by 64 -> each wave-iteration reads 256 contiguous
// bytes (coalesced). Expected total pixel reads ~ 90M (~358 MB), overlap
// served by L2/LLC; unique HBM traffic ~125 MB < the 134 MB full-image
// stream the scan kernel paid.
// ---------------------------------------------------------------------------
__global__ __launch_bounds__(THREADS) void box_direct_kernel(
    const float* __restrict__ img,
    const int* __restrict__ bboxes,
    float* __restrict__ ws_box) {

    const int box = blockIdx.x;              // 0 .. BATCH*NBOX-1
    const int s   = blockIdx.y;              // 0 .. NSLICE-1
    const int b   = box / NBOX;

    const int4 bb = ((const int4*)bboxes)[box];
    const int x1 = min(max(bb.x, 0), WDIM);
    const int y1 = min(max(bb.y, 0), WDIM);
    const int x2 = min(max(bb.z, 0), WDIM);
    const int y2 = min(max(bb.w, 0), WDIM);
    if (x2 <= x1 || y2 <= y1) return;        // ~75% of blocks exit here

    const int t    = threadIdx.x;
    const int lane = t & 63;
    const int wave = t >> 6;

    const float* base = img + (size_t)b * HDIM * WDIM;

    float acc = 0.0f;
    for (int y = y1 + s * 4 + wave; y < y2; y += NSLICE * 4) {
        const float* row = base + (size_t)y * WDIM;
        for (int x = x1 + lane; x < x2; x += 64) {
            acc += row[x];
        }
    }

    // wave butterfly reduction (64 lanes)
    #pragma unroll
    for (int off = 32; off > 0; off >>= 1)
        acc += __shfl_xor(acc, off, 64);

    if (lane == 0 && acc != 0.0f)
        atomicAdd(&ws_box[box], acc);
}

// ---------------------------------------------------------------------------
// Kernel 2: loss = sum over boxes of relu(1 - (valid ? box_sum : 0)).
// Single block; 3072 boxes.
// ---------------------------------------------------------------------------
__global__ void finalize_kernel(const float* __restrict__ ws_box,
                                const int* __restrict__ bboxes,
                                float* __restrict__ out) {
    __shared__ float red[THREADS / 64];
    const int t = threadIdx.x;
    float local = 0.0f;
    for (int idx = t; idx < BATCH * NBOX; idx += THREADS) {
        const int4 bb = ((const int4*)bboxes)[idx];
        int x1 = min(max(bb.x, 0), WDIM);
        int y1 = min(max(bb.y, 0), WDIM);
        int x2 = min(max(bb.z, 0), WDIM);
        int y2 = min(max(bb.w, 0), WDIM);
        bool valid = (x2 > x1) && (y2 > y1);
        float s = valid ? ws_box[idx] : 0.0f;
        local += fmaxf(1.0f - s, 0.0f);
    }
    #pragma unroll
    for (int off = 32; off > 0; off >>= 1)
        local += __shfl_down(local, off, 64);
    if ((t & 63) == 0) red[t >> 6] = local;
    __syncthreads();
    if (t == 0) {
        float r = 0.0f;
        #pragma unroll
        for (int w = 0; w < THREADS / 64; ++w) r += red[w];
        out[0] = r;
    }
}

// ---------------------------------------------------------------------------
extern "C" void kernel_launch(void* const* d_in, const int* in_sizes, int n_in,
                              void* d_out, int out_size, void* d_ws, size_t ws_size,
                              hipStream_t stream) {
    const float* img    = (const float*)d_in[0];   // (32,1,1024,1024) fp32
    const int*   bboxes = (const int*)d_in[1];     // (32,96,4) int32
    float* out = (float*)d_out;                    // scalar
    float* ws_box = (float*)d_ws;                  // BATCH*NBOX accumulators

    zero_ws_kernel<<<(BATCH * NBOX + THREADS - 1) / THREADS, THREADS, 0, stream>>>(ws_box);

    dim3 grid(BATCH * NBOX, NSLICE);
    box_direct_kernel<<<grid, THREADS, 0, stream>>>(img, bboxes, ws_box);

    finalize_kernel<<<1, THREADS, 0, stream>>>(ws_box, bboxes, out);
}

// Round 2
// 216.593 us; speedup vs baseline: 1.7563x; 1.7563x over previous
//
#include <hip/hip_runtime.h>

// Problem constants (from setup_inputs): B=32, H=W=1024, N=96 boxes/batch.
#define BATCH 32
#define HDIM 1024
#define WDIM 1024
#define NBOX 96
#define THREADS 256
#define NSLICE 16                          // slices per box; worst block = 1024*1024/16 px = 256 KB
#define NSTREAM (NSLICE * (THREADS / 64))  // 64 row-streams per box, row stride 64

// ---------------------------------------------------------------------------
// Kernel 0: zero the per-box accumulators in workspace (ws is poisoned 0xAA).
// ---------------------------------------------------------------------------
__global__ void zero_ws_kernel(float* __restrict__ ws) {
    int i = blockIdx.x * blockDim.x + threadIdx.x;
    if (i < BATCH * NBOX) ws[i] = 0.0f;
}

// ---------------------------------------------------------------------------
// Kernel 1: DIRECT box summation, latency-optimized.
// Round-1 post-mortem: scalar 4B loads + dependent acc + dynamic trip count
// -> ~1 load in flight/wave -> 9.5% HBM. Fixes here:
//   * float4 loads (aligned: xs = x1 & ~3; the <=2 edge vectors are
//     predicated per element; xs >= 0 and xs + 4*nvec <= 1024 so loads
//     never leave the row).
//   * two rows per iteration with independent accumulators (2x ILP).
//   * NSLICE=16 -> worst-case block work 256 KB; grid(x=slice, y=box) so a
//     box's slices are dispatch-adjacent (start/finish together).
// ---------------------------------------------------------------------------
__global__ __launch_bounds__(THREADS) void box_direct_kernel(
    const float* __restrict__ img,
    const int* __restrict__ bboxes,
    float* __restrict__ ws_box) {

    const int s   = blockIdx.x;            // 0 .. NSLICE-1
    const int box = blockIdx.y;            // 0 .. BATCH*NBOX-1
    const int b   = box / NBOX;

    const int4 bb = ((const int4*)bboxes)[box];
    const int x1 = min(max(bb.x, 0), WDIM);
    const int y1 = min(max(bb.y, 0), WDIM);
    const int x2 = min(max(bb.z, 0), WDIM);
    const int y2 = min(max(bb.w, 0), WDIM);
    if (x2 <= x1 || y2 <= y1) return;      // uniform branch; ~75% of blocks

    const int lane = threadIdx.x & 63;
    const int wave = threadIdx.x >> 6;
    const int r    = s * (THREADS / 64) + wave;   // row-stream id, 0..NSTREAM-1

    const int xs   = x1 & ~3;                     // 16B-aligned start column
    const int nvec = (x2 - xs + 3) >> 2;          // float4 slots covering [x1,x2)

    const float* base = img + (size_t)b * HDIM * WDIM + xs;

    float accA = 0.0f, accB = 0.0f;
    int y = y1 + r;

    // ---- paired rows: y and y+NSTREAM (independent load streams) ----
    for (; y + NSTREAM < y2; y += 2 * NSTREAM) {
        const float4* rowA = (const float4*)(base + (size_t)y * WDIM);
        const float4* rowB = (const float4*)(base + (size_t)(y + NSTREAM) * WDIM);
        for (int v = lane; v < nvec; v += 64) {
            float4 fA = rowA[v];
            float4 fB = rowB[v];
            const int x = xs + (v << 2);
            if (x >= x1 && x + 4 <= x2) {          // interior vector (common)
                accA += (fA.x + fA.y) + (fA.z + fA.w);
                accB += (fB.x + fB.y) + (fB.z + fB.w);
            } else {                                // <=2 edge vectors per row
                accA += (x     >= x1 && x     < x2) ? fA.x : 0.0f;
                accA += (x + 1 >= x1 && x + 1 < x2) ? fA.y : 0.0f;
                accA += (x + 2 >= x1 && x + 2 < x2) ? fA.z : 0.0f;
                accA += (x + 3 >= x1 && x + 3 < x2) ? fA.w : 0.0f;
                accB += (x     >= x1 && x     < x2) ? fB.x : 0.0f;
                accB += (x + 1 >= x1 && x + 1 < x2) ? fB.y : 0.0f;
                accB += (x + 2 >= x1 && x + 2 < x2) ? fB.z : 0.0f;
                accB += (x + 3 >= x1 && x + 3 < x2) ? fB.w : 0.0f;
            }
        }
    }

    // ---- leftover single row (at most one per stream) ----
    if (y < y2) {
        const float4* rowA = (const float4*)(base + (size_t)y * WDIM);
        for (int v = lane; v < nvec; v += 64) {
            float4 fA = rowA[v];
            const int x = xs + (v << 2);
            if (x >= x1 && x + 4 <= x2) {
                accA += (fA.x + fA.y) + (fA.z + fA.w);
            } else {
                accA += (x     >= x1 && x     < x2) ? fA.x : 0.0f;
                accA += (x + 1 >= x1 && x + 1 < x2) ? fA.y : 0.0f;
                accA += (x + 2 >= x1 && x + 2 < x2) ? fA.z : 0.0f;
                accA += (x + 3 >= x1 && x + 3 < x2) ? fA.w : 0.0f;
            }
        }
    }

    float acc = accA + accB;

    // wave butterfly reduction (64 lanes)
    #pragma unroll
    for (int off = 32; off > 0; off >>= 1)
        acc += __shfl_xor(acc, off, 64);

    if (lane == 0 && acc != 0.0f)
        atomicAdd(&ws_box[box], acc);
}

// ---------------------------------------------------------------------------
// Kernel 2: loss = sum over boxes of relu(1 - (valid ? box_sum : 0)).
// Single block; 3072 boxes.
// ---------------------------------------------------------------------------
__global__ void finalize_kernel(const float* __restrict__ ws_box,
                                const int* __restrict__ bboxes,
                                float* __restrict__ out) {
    __shared__ float red[THREADS / 64];
    const int t = threadIdx.x;
    float local = 0.0f;
    for (int idx = t; idx < BATCH * NBOX; idx += THREADS) {
        const int4 bb = ((const int4*)bboxes)[idx];
        int x1 = min(max(bb.x, 0), WDIM);
        int y1 = min(max(bb.y, 0), WDIM);
        int x2 = min(max(bb.z, 0), WDIM);
        int y2 = min(max(bb.w, 0), WDIM);
        bool valid = (x2 > x1) && (y2 > y1);
        float s = valid ? ws_box[idx] : 0.0f;
        local += fmaxf(1.0f - s, 0.0f);
    }
    #pragma unroll
    for (int off = 32; off > 0; off >>= 1)
        local += __shfl_down(local, off, 64);
    if ((t & 63) == 0) red[t >> 6] = local;
    __syncthreads();
    if (t == 0) {
        float r = 0.0f;
        #pragma unroll
        for (int w = 0; w < THREADS / 64; ++w) r += red[w];
        out[0] = r;
    }
}

// ---------------------------------------------------------------------------
extern "C" void kernel_launch(void* const* d_in, const int* in_sizes, int n_in,
                              void* d_out, int out_size, void* d_ws, size_t ws_size,
                              hipStream_t stream) {
    const float* img    = (const float*)d_in[0];   // (32,1,1024,1024) fp32
    const int*   bboxes = (const int*)d_in[1];     // (32,96,4) int32
    float* out = (float*)d_out;                    // scalar
    float* ws_box = (float*)d_ws;                  // BATCH*NBOX accumulators

    zero_ws_kernel<<<(BATCH * NBOX + THREADS - 1) / THREADS, THREADS, 0, stream>>>(ws_box);

    dim3 grid(NSLICE, BATCH * NBOX);
    box_direct_kernel<<<grid, THREADS, 0, stream>>>(img, bboxes, ws_box);

    finalize_kernel<<<1, THREADS, 0, stream>>>(ws_box, bboxes, out);
}

// Round 3
// 200.698 us; speedup vs baseline: 1.8954x; 1.0792x over previous
//
#include <hip/hip_runtime.h>

// Problem constants (from setup_inputs): B=32, H=W=1024, N=96 boxes/batch.
#define BATCH 32
#define HDIM 1024
#define WDIM 1024
#define NBOX 96
#define THREADS 256
#define WAVES (THREADS / 64)          // 4
#define ROWS_PER_WAVE 4
#define ROWS_PER_BLOCK (WAVES * ROWS_PER_WAVE)   // 16 -> grid 2048, uniform work

// ---------------------------------------------------------------------------
// Kernel 0: zero the per-box accumulators in workspace (ws is poisoned 0xAA).
// ---------------------------------------------------------------------------
__global__ void zero_ws_kernel(float* __restrict__ ws) {
    int i = blockIdx.x * blockDim.x + threadIdx.x;
    if (i < BATCH * NBOX) ws[i] = 0.0f;
}

// ---------------------------------------------------------------------------
// Kernel 1: barrier-free per-wave row scan + register-resident box lookup.
//
// Round-2 post-mortem: direct summation fetched 176 MB HBM (> the 134 MB
// image) and was imbalance/latency-bound (~60 us). This kernel reads the
// image exactly once with perfectly uniform blocks:
//   * wave w owns rows row0+4w .. +3 entirely; scans each 1024-wide row via
//     4 independent 64-lane shfl_up chains (scheduler interleaves them) and
//     stores the inclusive prefix to a WAVE-PRIVATE LDS segment
//     (consecutive-lane float4 -> conflict-free ds_write_b128).
//   * ZERO __syncthreads: all LDS hazards are intra-wave (compiler lgkmcnt).
//   * next row's 4 float4 loads are issued before the current row's scan,
//     so the shuffle chain hides under load latency.
//   * lane l owns boxes l and l+64 (register bbox, loaded once per block);
//     per row: <=2 segment-sum lookups P[x2-1]-P[x1-1] from LDS.
// ---------------------------------------------------------------------------
__global__ __launch_bounds__(THREADS) void row_scan_kernel(
    const float* __restrict__ img,
    const int* __restrict__ bboxes,
    float* __restrict__ ws_box) {

    __shared__ float P[WAVES][WDIM];   // 16 KB, wave-private segments

    const int t    = threadIdx.x;
    const int lane = t & 63;
    const int wave = t >> 6;

    const int blocks_per_batch = HDIM / ROWS_PER_BLOCK;   // 64
    const int b    = blockIdx.x / blocks_per_batch;
    const int row0 = (blockIdx.x % blocks_per_batch) * ROWS_PER_BLOCK
                   + wave * ROWS_PER_WAVE;

    // ---- per-lane owned boxes (lane, lane+64), loaded once ----
    const int4* bbp = (const int4*)bboxes + b * NBOX;
    const int4 ba = bbp[lane];
    const int ax1 = min(max(ba.x, 0), WDIM), ay1 = min(max(ba.y, 0), WDIM);
    const int ax2 = min(max(ba.z, 0), WDIM), ay2 = min(max(ba.w, 0), WDIM);
    const bool av = (ax2 > ax1);

    const bool hasB = lane < (NBOX - 64);   // lanes 0..31
    int bx1 = 0, by1 = 0, bx2 = 0, by2 = 0;
    bool bv = false;
    if (hasB) {
        const int4 bbv = bbp[64 + lane];
        bx1 = min(max(bbv.x, 0), WDIM); by1 = min(max(bbv.y, 0), WDIM);
        bx2 = min(max(bbv.z, 0), WDIM); by2 = min(max(bbv.w, 0), WDIM);
        bv = (bx2 > bx1);
    }

    float accA = 0.0f, accB = 0.0f;
    const float* rbase = img + ((size_t)b * HDIM + row0) * WDIM;
    float* Pw = P[wave];

    // prefetch row 0 (chunk k covers columns 4*lane + 256*k .. +3)
    float4 c0 = ((const float4*)rbase)[lane];
    float4 c1 = ((const float4*)rbase)[lane +  64];
    float4 c2 = ((const float4*)rbase)[lane + 128];
    float4 c3 = ((const float4*)rbase)[lane + 192];

    #pragma unroll
    for (int r = 0; r < ROWS_PER_WAVE; ++r) {
        float4 n0, n1, n2, n3;
        if (r + 1 < ROWS_PER_WAVE) {
            const float4* nr = (const float4*)(rbase + (size_t)(r + 1) * WDIM);
            n0 = nr[lane];       n1 = nr[lane +  64];
            n2 = nr[lane + 128]; n3 = nr[lane + 192];
        }

        // per-lane sequential prefix of 4 elements, per chunk
        const float s0 = c0.x + c0.y + c0.z + c0.w;
        const float s1 = c1.x + c1.y + c1.z + c1.w;
        const float s2 = c2.x + c2.y + c2.z + c2.w;
        const float s3 = c3.x + c3.y + c3.z + c3.w;

        // 4 independent wave-inclusive scans (interleaved by scheduler)
        float w0 = s0, w1 = s1, w2 = s2, w3 = s3;
        #pragma unroll
        for (int off = 1; off < 64; off <<= 1) {
            const float u0 = __shfl_up(w0, off, 64);
            const float u1 = __shfl_up(w1, off, 64);
            const float u2 = __shfl_up(w2, off, 64);
            const float u3 = __shfl_up(w3, off, 64);
            if (lane >= off) { w0 += u0; w1 += u1; w2 += u2; w3 += u3; }
        }
        // chunk totals -> chunk base offsets
        const float t0 = __shfl(w0, 63, 64);
        const float t1 = __shfl(w1, 63, 64);
        const float t2 = __shfl(w2, 63, 64);
        const float base1 = t0, base2 = t0 + t1, base3 = t0 + t1 + t2;

        // inclusive prefix at the last element of each lane's 4; subtract back
        float4 p0, p1, p2, p3;
        p0.w = w0;          p0.z = p0.w - c0.w; p0.y = p0.z - c0.z; p0.x = p0.y - c0.y;
        p1.w = base1 + w1;  p1.z = p1.w - c1.w; p1.y = p1.z - c1.z; p1.x = p1.y - c1.y;
        p2.w = base2 + w2;  p2.z = p2.w - c2.w; p2.y = p2.z - c2.z; p2.x = p2.y - c2.y;
        p3.w = base3 + w3;  p3.z = p3.w - c3.w; p3.y = p3.z - c3.z; p3.x = p3.y - c3.y;

        // conflict-free float4 stores; word index == column index
        ((float4*)Pw)[lane]       = p0;
        ((float4*)Pw)[lane +  64] = p1;
        ((float4*)Pw)[lane + 128] = p2;
        ((float4*)Pw)[lane + 192] = p3;

        // ---- box lookups for this row (intra-wave LDS RAW; no barrier) ----
        const int y = row0 + r;
        if (av && (ay1 <= y) && (y < ay2))
            accA += Pw[ax2 - 1] - (ax1 > 0 ? Pw[ax1 - 1] : 0.0f);
        if (bv && (by1 <= y) && (y < by2))
            accB += Pw[bx2 - 1] - (bx1 > 0 ? Pw[bx1 - 1] : 0.0f);

        c0 = n0; c1 = n1; c2 = n2; c3 = n3;
    }

    if (accA != 0.0f)         atomicAdd(&ws_box[b * NBOX + lane],      accA);
    if (hasB && accB != 0.0f) atomicAdd(&ws_box[b * NBOX + 64 + lane], accB);
}

// ---------------------------------------------------------------------------
// Kernel 2: loss = sum over boxes of relu(1 - (valid ? box_sum : 0)).
// Single block; 3072 boxes.
// ---------------------------------------------------------------------------
__global__ void finalize_kernel(const float* __restrict__ ws_box,
                                const int* __restrict__ bboxes,
                                float* __restrict__ out) {
    __shared__ float red[THREADS / 64];
    const int t = threadIdx.x;
    float local = 0.0f;
    for (int idx = t; idx < BATCH * NBOX; idx += THREADS) {
        const int4 bb = ((const int4*)bboxes)[idx];
        int x1 = min(max(bb.x, 0), WDIM);
        int y1 = min(max(bb.y, 0), WDIM);
        int x2 = min(max(bb.z, 0), WDIM);
        int y2 = min(max(bb.w, 0), WDIM);
        bool valid = (x2 > x1) && (y2 > y1);
        float s = valid ? ws_box[idx] : 0.0f;
        local += fmaxf(1.0f - s, 0.0f);
    }
    #pragma unroll
    for (int off = 32; off > 0; off >>= 1)
        local += __shfl_down(local, off, 64);
    if ((t & 63) == 0) red[t >> 6] = local;
    __syncthreads();
    if (t == 0) {
        float r = 0.0f;
        #pragma unroll
        for (int w = 0; w < THREADS / 64; ++w) r += red[w];
        out[0] = r;
    }
}

// ---------------------------------------------------------------------------
extern "C" void kernel_launch(void* const* d_in, const int* in_sizes, int n_in,
                              void* d_out, int out_size, void* d_ws, size_t ws_size,
                              hipStream_t stream) {
    const float* img    = (const float*)d_in[0];   // (32,1,1024,1024) fp32
    const int*   bboxes = (const int*)d_in[1];     // (32,96,4) int32
    float* out = (float*)d_out;                    // scalar
    float* ws_box = (float*)d_ws;                  // BATCH*NBOX accumulators

    zero_ws_kernel<<<(BATCH * NBOX + THREADS - 1) / THREADS, THREADS, 0, stream>>>(ws_box);

    const int nblocks = BATCH * HDIM / ROWS_PER_BLOCK;   // 2048 uniform blocks
    row_scan_kernel<<<nblocks, THREADS, 0, stream>>>(img, bboxes, ws_box);

    finalize_kernel<<<1, THREADS, 0, stream>>>(ws_box, bboxes, out);
}

// Round 4
// 197.338 us; speedup vs baseline: 1.9277x; 1.0170x over previous
//
#include <hip/hip_runtime.h>

// Problem constants (from setup_inputs): B=32, H=W=1024, N=96 boxes/batch.
#define BATCH 32
#define HDIM 1024
#define WDIM 1024
#define NBOX 96
#define THREADS 256
#define WAVES (THREADS / 64)          // 4
#define ROWS_PER_WAVE 4
#define ROWS_PER_BLOCK (WAVES * ROWS_PER_WAVE)   // 16 -> grid 2048, uniform work

// ---------------------------------------------------------------------------
// DPP helpers: 64-lane inclusive scan with ZERO ds_bpermute.
// Round-3 post-mortem: barrier removal changed nothing vs round-0 (200.25 vs
// 200.70 us) -> the shared bottleneck is the 6-step dependent __shfl_up
// chain (each ds_bpermute ~40-60 cyc) = ~300-400 cyc serial per row.
// Replace with 4 x v_add_f32 row_shr DPP (intra-16-lane scan, ~4 cyc each)
// + 3 readlane/cndmask to stitch the four 16-lane rows. Critical path per
// row-scan: ~30 cyc, all VALU.
// ---------------------------------------------------------------------------
__device__ __forceinline__ float dpp_scan16(float x) {
    int v;
    v = __builtin_amdgcn_update_dpp(0, __builtin_bit_cast(int, x), 0x111, 0xF, 0xF, true); // row_shr:1
    x += __builtin_bit_cast(float, v);
    v = __builtin_amdgcn_update_dpp(0, __builtin_bit_cast(int, x), 0x112, 0xF, 0xF, true); // row_shr:2
    x += __builtin_bit_cast(float, v);
    v = __builtin_amdgcn_update_dpp(0, __builtin_bit_cast(int, x), 0x114, 0xF, 0xF, true); // row_shr:4
    x += __builtin_bit_cast(float, v);
    v = __builtin_amdgcn_update_dpp(0, __builtin_bit_cast(int, x), 0x118, 0xF, 0xF, true); // row_shr:8
    x += __builtin_bit_cast(float, v);
    return x;
}
__device__ __forceinline__ float rl(float x, int l) {   // uniform readlane
    return __builtin_bit_cast(float, __builtin_amdgcn_readlane(__builtin_bit_cast(int, x), l));
}

// ---------------------------------------------------------------------------
// Kernel 0: zero the per-box accumulators in workspace (ws is poisoned 0xAA).
// ---------------------------------------------------------------------------
__global__ void zero_ws_kernel(float* __restrict__ ws) {
    int i = blockIdx.x * blockDim.x + threadIdx.x;
    if (i < BATCH * NBOX) ws[i] = 0.0f;
}

// ---------------------------------------------------------------------------
// Kernel 1: barrier-free per-wave row scan, DPP-based (no bpermute chains).
// Wave w owns rows row0+4w..+3; lane l owns columns 4l+256k (k=0..3), so
// float4 loads are coalesced and the float4 LDS stores are conflict-free.
// Lane l owns boxes l and l+64 (register-resident bbox); per row <=2
// segment lookups P[x2-1]-P[x1-1] from the wave-private LDS prefix.
// ---------------------------------------------------------------------------
__global__ __launch_bounds__(THREADS) void row_scan_kernel(
    const float* __restrict__ img,
    const int* __restrict__ bboxes,
    float* __restrict__ ws_box) {

    __shared__ float P[WAVES][WDIM];   // 16 KB, wave-private segments

    const int t    = threadIdx.x;
    const int lane = t & 63;
    const int wave = t >> 6;
    const int g    = lane >> 4;        // DPP-row index 0..3

    const int blocks_per_batch = HDIM / ROWS_PER_BLOCK;   // 64
    const int b    = blockIdx.x / blocks_per_batch;
    const int row0 = (blockIdx.x % blocks_per_batch) * ROWS_PER_BLOCK
                   + wave * ROWS_PER_WAVE;

    // ---- per-lane owned boxes (lane, lane+64), loaded once ----
    const int4* bbp = (const int4*)bboxes + b * NBOX;
    const int4 ba = bbp[lane];
    const int ax1 = min(max(ba.x, 0), WDIM), ay1 = min(max(ba.y, 0), WDIM);
    const int ax2 = min(max(ba.z, 0), WDIM), ay2 = min(max(ba.w, 0), WDIM);
    const bool av = (ax2 > ax1);

    const bool hasB = lane < (NBOX - 64);   // lanes 0..31
    int bx1 = 0, by1 = 0, bx2 = 0, by2 = 0;
    bool bv = false;
    if (hasB) {
        const int4 bbv = bbp[64 + lane];
        bx1 = min(max(bbv.x, 0), WDIM); by1 = min(max(bbv.y, 0), WDIM);
        bx2 = min(max(bbv.z, 0), WDIM); by2 = min(max(bbv.w, 0), WDIM);
        bv = (bx2 > bx1);
    }

    float accA = 0.0f, accB = 0.0f;
    const float* rbase = img + ((size_t)b * HDIM + row0) * WDIM;
    float* Pw = P[wave];

    // prefetch row 0 (chunk k covers columns 4*lane + 256*k .. +3)
    float4 c0 = ((const float4*)rbase)[lane];
    float4 c1 = ((const float4*)rbase)[lane +  64];
    float4 c2 = ((const float4*)rbase)[lane + 128];
    float4 c3 = ((const float4*)rbase)[lane + 192];

    #pragma unroll
    for (int r = 0; r < ROWS_PER_WAVE; ++r) {
        float4 n0, n1, n2, n3;
        if (r + 1 < ROWS_PER_WAVE) {
            const float4* nr = (const float4*)(rbase + (size_t)(r + 1) * WDIM);
            n0 = nr[lane];       n1 = nr[lane +  64];
            n2 = nr[lane + 128]; n3 = nr[lane + 192];
        }

        // per-lane sequential sum of 4 elements, per chunk
        const float s0 = c0.x + c0.y + c0.z + c0.w;
        const float s1 = c1.x + c1.y + c1.z + c1.w;
        const float s2 = c2.x + c2.y + c2.z + c2.w;
        const float s3 = c3.x + c3.y + c3.z + c3.w;

        // 16-lane DPP scans (4 independent, ~30 cyc critical path each)
        float q0 = dpp_scan16(s0);
        float q1 = dpp_scan16(s1);
        float q2 = dpp_scan16(s2);
        float q3 = dpp_scan16(s3);

        // stitch the four 16-lane rows of each chunk: base for DPP-row g
        const float a0_0 = rl(q0, 15), a0_1 = rl(q0, 31), a0_2 = rl(q0, 47), a0_3 = rl(q0, 63);
        const float a1_0 = rl(q1, 15), a1_1 = rl(q1, 31), a1_2 = rl(q1, 47), a1_3 = rl(q1, 63);
        const float a2_0 = rl(q2, 15), a2_1 = rl(q2, 31), a2_2 = rl(q2, 47), a2_3 = rl(q2, 63);
        const float a3_0 = rl(q3, 15), a3_1 = rl(q3, 31), a3_2 = rl(q3, 47), a3_3 = rl(q3, 63);

        float w0 = q0 + ((g >= 1) ? a0_0 : 0.0f) + ((g >= 2) ? a0_1 : 0.0f) + ((g >= 3) ? a0_2 : 0.0f);
        float w1 = q1 + ((g >= 1) ? a1_0 : 0.0f) + ((g >= 2) ? a1_1 : 0.0f) + ((g >= 3) ? a1_2 : 0.0f);
        float w2 = q2 + ((g >= 1) ? a2_0 : 0.0f) + ((g >= 2) ? a2_1 : 0.0f) + ((g >= 3) ? a2_2 : 0.0f);
        float w3 = q3 + ((g >= 1) ? a3_0 : 0.0f) + ((g >= 2) ? a3_1 : 0.0f) + ((g >= 3) ? a3_2 : 0.0f);

        // chunk totals (uniform) -> chunk base offsets
        const float t0 = a0_0 + a0_1 + a0_2 + a0_3;
        const float t1 = a1_0 + a1_1 + a1_2 + a1_3;
        const float t2 = a2_0 + a2_1 + a2_2 + a2_3;
        const float base1 = t0, base2 = t0 + t1, base3 = t0 + t1 + t2;

        // inclusive prefix at the last element of each lane's 4; subtract back
        float4 p0, p1, p2, p3;
        p0.w = w0;          p0.z = p0.w - c0.w; p0.y = p0.z - c0.z; p0.x = p0.y - c0.y;
        p1.w = base1 + w1;  p1.z = p1.w - c1.w; p1.y = p1.z - c1.z; p1.x = p1.y - c1.y;
        p2.w = base2 + w2;  p2.z = p2.w - c2.w; p2.y = p2.z - c2.z; p2.x = p2.y - c2.y;
        p3.w = base3 + w3;  p3.z = p3.w - c3.w; p3.y = p3.z - c3.z; p3.x = p3.y - c3.y;

        // conflict-free float4 stores; word index == column index
        ((float4*)Pw)[lane]       = p0;
        ((float4*)Pw)[lane +  64] = p1;
        ((float4*)Pw)[lane + 128] = p2;
        ((float4*)Pw)[lane + 192] = p3;

        // ---- box lookups for this row (intra-wave LDS RAW; no barrier) ----
        const int y = row0 + r;
        if (av && (ay1 <= y) && (y < ay2))
            accA += Pw[ax2 - 1] - (ax1 > 0 ? Pw[ax1 - 1] : 0.0f);
        if (bv && (by1 <= y) && (y < by2))
            accB += Pw[bx2 - 1] - (bx1 > 0 ? Pw[bx1 - 1] : 0.0f);

        c0 = n0; c1 = n1; c2 = n2; c3 = n3;
    }

    if (accA != 0.0f)         atomicAdd(&ws_box[b * NBOX + lane],      accA);
    if (hasB && accB != 0.0f) atomicAdd(&ws_box[b * NBOX + 64 + lane], accB);
}

// ---------------------------------------------------------------------------
// Kernel 2: loss = sum over boxes of relu(1 - (valid ? box_sum : 0)).
// Single block; 3072 boxes.
// ---------------------------------------------------------------------------
__global__ void finalize_kernel(const float* __restrict__ ws_box,
                                const int* __restrict__ bboxes,
                                float* __restrict__ out) {
    __shared__ float red[THREADS / 64];
    const int t = threadIdx.x;
    float local = 0.0f;
    for (int idx = t; idx < BATCH * NBOX; idx += THREADS) {
        const int4 bb = ((const int4*)bboxes)[idx];
        int x1 = min(max(bb.x, 0), WDIM);
        int y1 = min(max(bb.y, 0), WDIM);
        int x2 = min(max(bb.z, 0), WDIM);
        int y2 = min(max(bb.w, 0), WDIM);
        bool valid = (x2 > x1) && (y2 > y1);
        float s = valid ? ws_box[idx] : 0.0f;
        local += fmaxf(1.0f - s, 0.0f);
    }
    #pragma unroll
    for (int off = 32; off > 0; off >>= 1)
        local += __shfl_down(local, off, 64);
    if ((t & 63) == 0) red[t >> 6] = local;
    __syncthreads();
    if (t == 0) {
        float r = 0.0f;
        #pragma unroll
        for (int w = 0; w < THREADS / 64; ++w) r += red[w];
        out[0] = r;
    }
}

// ---------------------------------------------------------------------------
extern "C" void kernel_launch(void* const* d_in, const int* in_sizes, int n_in,
                              void* d_out, int out_size, void* d_ws, size_t ws_size,
                              hipStream_t stream) {
    const float* img    = (const float*)d_in[0];   // (32,1,1024,1024) fp32
    const int*   bboxes = (const int*)d_in[1];     // (32,96,4) int32
    float* out = (float*)d_out;                    // scalar
    float* ws_box = (float*)d_ws;                  // BATCH*NBOX accumulators

    zero_ws_kernel<<<(BATCH * NBOX + THREADS - 1) / THREADS, THREADS, 0, stream>>>(ws_box);

    const int nblocks = BATCH * HDIM / ROWS_PER_BLOCK;   // 2048 uniform blocks
    row_scan_kernel<<<nblocks, THREADS, 0, stream>>>(img, bboxes, ws_box);

    finalize_kernel<<<1, THREADS, 0, stream>>>(ws_box, bboxes, out);
}